// Round 1
// baseline (1017.593 us; speedup 1.0000x reference)
//
#include <hip/hip_runtime.h>
#include <math.h>

#define TS 2048   // sequence length T
#define KD 1024   // model dim K
#define NH 16     // heads
#define SD 64     // head dim
#define MB 4096   // B*T rows

// ---------------------------------------------------------------------------
// GEMM: C = A @ W^T (+bias).  A: MB x KD row-major, W: N(=KD) x KD row-major.
// 128x128 tile, BK=16, 256 threads, 8x8 micro-tile. blockIdx.z picks (W, C)
// so the three QKV projections run as one launch (768 blocks -> 3/CU).
// ---------------------------------------------------------------------------
__global__ __launch_bounds__(256)
void gemm_bt(const float* __restrict__ A,
             const float* __restrict__ W0, const float* __restrict__ W1,
             const float* __restrict__ W2,
             float* __restrict__ C0, float* __restrict__ C1, float* __restrict__ C2,
             const float* __restrict__ bias)
{
    const float* W = W0; float* C = C0;
    if (blockIdx.z == 1) { W = W1; C = C1; }
    else if (blockIdx.z == 2) { W = W2; C = C2; }

    __shared__ float As[16][132];   // k-major: As[kk][m], pad 132 (fp32, 16B-aligned rows)
    __shared__ float Ws[16][132];   // k-major: Ws[kk][n]

    const int tid = threadIdx.x;
    const int tx = tid & 15;        // col group (n)
    const int ty = tid >> 4;        // row group (m)
    const int m0 = blockIdx.y * 128;
    const int n0 = blockIdx.x * 128;

    float acc[8][8];
#pragma unroll
    for (int i = 0; i < 8; ++i)
#pragma unroll
        for (int j = 0; j < 8; ++j) acc[i][j] = 0.f;

    for (int k0 = 0; k0 < KD; k0 += 16) {
#pragma unroll
        for (int i = 0; i < 2; ++i) {
            int f   = tid + i * 256;      // 0..511 float4 slots per operand
            int row = f >> 2;             // 0..127
            int c4  = (f & 3) << 2;       // 0,4,8,12
            float4 va = *(const float4*)(A + (size_t)(m0 + row) * KD + k0 + c4);
            float4 vw = *(const float4*)(W + (size_t)(n0 + row) * KD + k0 + c4);
            As[c4 + 0][row] = va.x; As[c4 + 1][row] = va.y;
            As[c4 + 2][row] = va.z; As[c4 + 3][row] = va.w;
            Ws[c4 + 0][row] = vw.x; Ws[c4 + 1][row] = vw.y;
            Ws[c4 + 2][row] = vw.z; Ws[c4 + 3][row] = vw.w;
        }
        __syncthreads();
#pragma unroll
        for (int kk = 0; kk < 16; ++kk) {
            float a[8], b[8];
            *(float4*)(a)     = *(const float4*)&As[kk][ty * 8];
            *(float4*)(a + 4) = *(const float4*)&As[kk][ty * 8 + 4];
            *(float4*)(b)     = *(const float4*)&Ws[kk][tx * 8];
            *(float4*)(b + 4) = *(const float4*)&Ws[kk][tx * 8 + 4];
#pragma unroll
            for (int i = 0; i < 8; ++i)
#pragma unroll
                for (int j = 0; j < 8; ++j)
                    acc[i][j] = fmaf(a[i], b[j], acc[i][j]);
        }
        __syncthreads();
    }

    float bj[8];
#pragma unroll
    for (int j = 0; j < 8; ++j) bj[j] = bias ? bias[n0 + tx * 8 + j] : 0.f;

#pragma unroll
    for (int i = 0; i < 8; ++i) {
        int m = m0 + ty * 8 + i;
        float* Cp = C + (size_t)m * KD + n0 + tx * 8;
        float4 v0 = make_float4(acc[i][0] + bj[0], acc[i][1] + bj[1],
                                acc[i][2] + bj[2], acc[i][3] + bj[3]);
        float4 v1 = make_float4(acc[i][4] + bj[4], acc[i][5] + bj[5],
                                acc[i][6] + bj[6], acc[i][7] + bj[7]);
        *(float4*)(Cp)     = v0;
        *(float4*)(Cp + 4) = v1;
    }
}

// ---------------------------------------------------------------------------
// Flash attention (fp32): one block per (b, h, 64-row q tile).
// Online softmax over 32 key tiles of 64. 4x4 micro-tiles for QK^T and PV.
// Q,K stored d-major (transposed) in LDS so rank-1 updates read float4.
// Key mask: masked keys -> S=-inf -> P=0 (guarded for all-masked prefixes).
// ---------------------------------------------------------------------------
__global__ __launch_bounds__(256)
void attn(const float* __restrict__ Q, const float* __restrict__ Kb,
          const float* __restrict__ V, const int* __restrict__ mask,
          float* __restrict__ Y)
{
    const int qt = blockIdx.x;   // 0..31
    const int h  = blockIdx.y;   // 0..15
    const int b  = blockIdx.z;   // 0..1

    __shared__ float Qt[64][68];   // Qt[d][r]
    __shared__ float Kt[64][68];   // Kt[d][c]
    __shared__ float Vs[64][68];   // Vs[c][d]
    __shared__ float Pt[64][68];   // Pt[c][r]
    __shared__ float red[64][17];  // row-reduction partials
    __shared__ float m_s[64], l_s[64], al_s[64];
    __shared__ int   km[64];

    const int tid = threadIdx.x;
    const int tx = tid & 15;       // col group: c0 = 4*tx
    const int ty = tid >> 4;       // row group: r0 = 4*ty
    const int r0 = ty * 4;
    const int c0 = tx * 4;

    const size_t base = (size_t)b * TS * KD + (size_t)h * SD;  // + t*KD per row

    // stage Q tile (transposed)
#pragma unroll
    for (int i = 0; i < 4; ++i) {
        int f   = tid + i * 256;       // 0..1023 float4 slots
        int row = f >> 4;              // 0..63
        int c4  = (f & 15) << 2;       // 0..60
        float4 v = *(const float4*)(Q + base + (size_t)(qt * 64 + row) * KD + c4);
        Qt[c4 + 0][row] = v.x; Qt[c4 + 1][row] = v.y;
        Qt[c4 + 2][row] = v.z; Qt[c4 + 3][row] = v.w;
    }
    if (tid < 64) { m_s[tid] = -INFINITY; l_s[tid] = 0.f; }

    float O[4][4];
#pragma unroll
    for (int i = 0; i < 4; ++i)
#pragma unroll
        for (int j = 0; j < 4; ++j) O[i][j] = 0.f;

    for (int kt = 0; kt < TS / 64; ++kt) {
        __syncthreads();   // protect Kt/Vs/km/Pt from previous iteration's readers
        // stage K (transposed) and V (natural) tiles + key mask
#pragma unroll
        for (int i = 0; i < 4; ++i) {
            int f   = tid + i * 256;
            int row = f >> 4;
            int c4  = (f & 15) << 2;
            float4 vk = *(const float4*)(Kb + base + (size_t)(kt * 64 + row) * KD + c4);
            Kt[c4 + 0][row] = vk.x; Kt[c4 + 1][row] = vk.y;
            Kt[c4 + 2][row] = vk.z; Kt[c4 + 3][row] = vk.w;
            float4 vv = *(const float4*)(V + base + (size_t)(kt * 64 + row) * KD + c4);
            *(float4*)&Vs[row][c4] = vv;
        }
        if (tid < 64) km[tid] = mask[b * TS + kt * 64 + tid];
        __syncthreads();

        // S = Q K^T (4x4 per thread), then key-mask
        float S[4][4];
#pragma unroll
        for (int i = 0; i < 4; ++i)
#pragma unroll
            for (int j = 0; j < 4; ++j) S[i][j] = 0.f;
        for (int d = 0; d < 64; ++d) {
            float4 a  = *(const float4*)&Qt[d][r0];
            float4 bb = *(const float4*)&Kt[d][c0];
            const float av[4] = {a.x, a.y, a.z, a.w};
            const float bv[4] = {bb.x, bb.y, bb.z, bb.w};
#pragma unroll
            for (int i = 0; i < 4; ++i)
#pragma unroll
                for (int j = 0; j < 4; ++j)
                    S[i][j] = fmaf(av[i], bv[j], S[i][j]);
        }
#pragma unroll
        for (int j = 0; j < 4; ++j) {
            if (km[c0 + j] == 0) {
#pragma unroll
                for (int i = 0; i < 4; ++i) S[i][j] = -INFINITY;
            }
        }
        // row-max partials
#pragma unroll
        for (int i = 0; i < 4; ++i) {
            float mx = fmaxf(fmaxf(S[i][0], S[i][1]), fmaxf(S[i][2], S[i][3]));
            red[r0 + i][tx] = mx;
        }
        __syncthreads();
        if (tid < 64) {
            float mt = -INFINITY;
#pragma unroll
            for (int q = 0; q < 16; ++q) mt = fmaxf(mt, red[tid][q]);
            float mp = m_s[tid];
            float mn = fmaxf(mp, mt);
            al_s[tid] = (mp == -INFINITY) ? 0.f : __expf(mp - mn);
            m_s[tid]  = mn;
        }
        __syncthreads();

        // P = exp(S - m), store transposed, row-sum partials
        float rs[4];
#pragma unroll
        for (int i = 0; i < 4; ++i) {
            float m = m_s[r0 + i];
            rs[i] = 0.f;
#pragma unroll
            for (int j = 0; j < 4; ++j) {
                float s = S[i][j];
                float p = (s == -INFINITY) ? 0.f : __expf(s - m);
                S[i][j] = p;
                rs[i] += p;
            }
        }
#pragma unroll
        for (int j = 0; j < 4; ++j) {
            float4 pv = make_float4(S[0][j], S[1][j], S[2][j], S[3][j]);
            *(float4*)&Pt[c0 + j][r0] = pv;
        }
#pragma unroll
        for (int i = 0; i < 4; ++i) red[r0 + i][tx] = rs[i];
        __syncthreads();
        if (tid < 64) {
            float s = 0.f;
#pragma unroll
            for (int q = 0; q < 16; ++q) s += red[tid][q];
            l_s[tid] = l_s[tid] * al_s[tid] + s;
        }
        // O = O*alpha + P @ V   (Pt complete as of last sync; al_s stable)
#pragma unroll
        for (int i = 0; i < 4; ++i) {
            float al = al_s[r0 + i];
#pragma unroll
            for (int j = 0; j < 4; ++j) O[i][j] *= al;
        }
        for (int c = 0; c < 64; ++c) {
            float4 a  = *(const float4*)&Pt[c][r0];
            float4 bb = *(const float4*)&Vs[c][c0];
            const float av[4] = {a.x, a.y, a.z, a.w};
            const float bv[4] = {bb.x, bb.y, bb.z, bb.w};
#pragma unroll
            for (int i = 0; i < 4; ++i)
#pragma unroll
                for (int j = 0; j < 4; ++j)
                    O[i][j] = fmaf(av[i], bv[j], O[i][j]);
        }
    }
    __syncthreads();   // l_s final

#pragma unroll
    for (int i = 0; i < 4; ++i) {
        float inv = 1.f / l_s[r0 + i];
        float4 v = make_float4(O[i][0] * inv, O[i][1] * inv,
                               O[i][2] * inv, O[i][3] * inv);
        *(float4*)(Y + base + (size_t)(qt * 64 + r0 + i) * KD + c0) = v;
    }
}

// ---------------------------------------------------------------------------
extern "C" void kernel_launch(void* const* d_in, const int* in_sizes, int n_in,
                              void* d_out, int out_size, void* d_ws, size_t ws_size,
                              hipStream_t stream) {
    const float* x    = (const float*)d_in[0];
    const int*   mask = (const int*)d_in[1];
    const float* Wk   = (const float*)d_in[2];
    const float* Wq   = (const float*)d_in[3];
    const float* Wv   = (const float*)d_in[4];
    const float* Wu   = (const float*)d_in[5];
    const float* bu   = (const float*)d_in[6];
    float* out = (float*)d_out;

    float* Qb = (float*)d_ws;                 // 4096x1024 fp32
    float* Kb = Qb + (size_t)MB * KD;
    float* Vb = Kb + (size_t)MB * KD;
    float* Yb = Vb + (size_t)MB * KD;         // attention output (pre-Wu)

    dim3 blk(256);
    // Q, K, V projections in one launch (z picks the weight/output)
    gemm_bt<<<dim3(8, 32, 3), blk, 0, stream>>>(x, Wq, Wk, Wv, Qb, Kb, Vb, nullptr);
    // flash attention
    attn<<<dim3(32, NH, 2), blk, 0, stream>>>(Qb, Kb, Vb, mask, Yb);
    // output projection + bias
    gemm_bt<<<dim3(8, 32, 1), blk, 0, stream>>>(Yb, Wu, nullptr, nullptr,
                                                out, nullptr, nullptr, bu);
}

// Round 2
// 953.027 us; speedup vs baseline: 1.0677x; 1.0677x over previous
//
#include <hip/hip_runtime.h>
#include <math.h>

#define TS 2048   // sequence length T
#define KD 1024   // model dim K
#define NH 16     // heads
#define SD 64     // head dim
#define MB 4096   // B*T rows

typedef __attribute__((ext_vector_type(8))) short bf16x8;   // 8 bf16 (4 VGPRs)
typedef __attribute__((ext_vector_type(4))) float f32x4;    // MFMA accumulator
typedef unsigned short ushort_t;

__device__ inline ushort_t f2bf(float f) {            // round-to-nearest-even
    union { float f; unsigned u; } v; v.f = f;
    unsigned r = v.u + 0x7fff + ((v.u >> 16) & 1);
    return (ushort_t)(r >> 16);
}
__device__ inline float bf2f(ushort_t u) {
    union { unsigned u; float f; } v; v.u = ((unsigned)u) << 16;
    return v.f;
}

// ---------------------------------------------------------------------------
// fp32 GEMM: C = A @ W^T (+bias) — unchanged from round 1 (known good).
// ---------------------------------------------------------------------------
__global__ __launch_bounds__(256)
void gemm_bt(const float* __restrict__ A,
             const float* __restrict__ W0, const float* __restrict__ W1,
             const float* __restrict__ W2,
             float* __restrict__ C0, float* __restrict__ C1, float* __restrict__ C2,
             const float* __restrict__ bias)
{
    const float* W = W0; float* C = C0;
    if (blockIdx.z == 1) { W = W1; C = C1; }
    else if (blockIdx.z == 2) { W = W2; C = C2; }

    __shared__ float As[16][132];
    __shared__ float Ws[16][132];

    const int tid = threadIdx.x;
    const int tx = tid & 15;
    const int ty = tid >> 4;
    const int m0 = blockIdx.y * 128;
    const int n0 = blockIdx.x * 128;

    float acc[8][8];
#pragma unroll
    for (int i = 0; i < 8; ++i)
#pragma unroll
        for (int j = 0; j < 8; ++j) acc[i][j] = 0.f;

    for (int k0 = 0; k0 < KD; k0 += 16) {
#pragma unroll
        for (int i = 0; i < 2; ++i) {
            int f   = tid + i * 256;
            int row = f >> 2;
            int c4  = (f & 3) << 2;
            float4 va = *(const float4*)(A + (size_t)(m0 + row) * KD + k0 + c4);
            float4 vw = *(const float4*)(W + (size_t)(n0 + row) * KD + k0 + c4);
            As[c4 + 0][row] = va.x; As[c4 + 1][row] = va.y;
            As[c4 + 2][row] = va.z; As[c4 + 3][row] = va.w;
            Ws[c4 + 0][row] = vw.x; Ws[c4 + 1][row] = vw.y;
            Ws[c4 + 2][row] = vw.z; Ws[c4 + 3][row] = vw.w;
        }
        __syncthreads();
#pragma unroll
        for (int kk = 0; kk < 16; ++kk) {
            float a[8], b[8];
            *(float4*)(a)     = *(const float4*)&As[kk][ty * 8];
            *(float4*)(a + 4) = *(const float4*)&As[kk][ty * 8 + 4];
            *(float4*)(b)     = *(const float4*)&Ws[kk][tx * 8];
            *(float4*)(b + 4) = *(const float4*)&Ws[kk][tx * 8 + 4];
#pragma unroll
            for (int i = 0; i < 8; ++i)
#pragma unroll
                for (int j = 0; j < 8; ++j)
                    acc[i][j] = fmaf(a[i], b[j], acc[i][j]);
        }
        __syncthreads();
    }

    float bj[8];
#pragma unroll
    for (int j = 0; j < 8; ++j) bj[j] = bias ? bias[n0 + tx * 8 + j] : 0.f;

#pragma unroll
    for (int i = 0; i < 8; ++i) {
        int m = m0 + ty * 8 + i;
        float* Cp = C + (size_t)m * KD + n0 + tx * 8;
        float4 v0 = make_float4(acc[i][0] + bj[0], acc[i][1] + bj[1],
                                acc[i][2] + bj[2], acc[i][3] + bj[3]);
        float4 v1 = make_float4(acc[i][4] + bj[4], acc[i][5] + bj[5],
                                acc[i][6] + bj[6], acc[i][7] + bj[7]);
        *(float4*)(Cp)     = v0;
        *(float4*)(Cp + 4) = v1;
    }
}

// ---------------------------------------------------------------------------
// Split fp32 [MB][KD] into hi/lo bf16 with per-head layout [b*NH+h][t][SD].
// ---------------------------------------------------------------------------
__global__ __launch_bounds__(256)
void conv_split(const float* __restrict__ X, ushort_t* __restrict__ H,
                ushort_t* __restrict__ L)
{
    int idx = blockIdx.x * 256 + threadIdx.x;    // one float4 per thread
    int row = idx >> 8;                          // KD/4 = 256 float4/row
    int c4  = (idx & 255) << 2;
    float4 v = *(const float4*)(X + (size_t)row * KD + c4);
    int b = row >> 11, t = row & (TS - 1);
    int h = c4 >> 6,   d = c4 & 63;
    size_t o = ((size_t)(b * NH + h) * TS + t) * SD + d;
    float x[4] = {v.x, v.y, v.z, v.w};
    ushort_t hh[4], ll[4];
#pragma unroll
    for (int j = 0; j < 4; ++j) {
        hh[j] = f2bf(x[j]);
        ll[j] = f2bf(x[j] - bf2f(hh[j]));
    }
    *(ushort4*)(H + o) = make_ushort4(hh[0], hh[1], hh[2], hh[3]);
    *(ushort4*)(L + o) = make_ushort4(ll[0], ll[1], ll[2], ll[3]);
}

// ---------------------------------------------------------------------------
// V fp32 [b][t][h*64+d] -> bf16 transposed per head: Vt[b*NH+h][d][t]
// ---------------------------------------------------------------------------
__global__ __launch_bounds__(256)
void conv_vt(const float* __restrict__ V, ushort_t* __restrict__ Vt)
{
    __shared__ ushort_t Tl[64][72];
    int bh = blockIdx.y;
    int b = bh >> 4, h = bh & 15;
    int t0 = blockIdx.x * 64;
#pragma unroll
    for (int i = 0; i < 4; ++i) {
        int f = threadIdx.x + i * 256;     // 1024 float4 slots
        int r = f >> 4;                    // t row 0..63
        int c = (f & 15) << 2;             // d 0..60
        float4 v = *(const float4*)(V + (size_t)(b * TS + t0 + r) * KD + h * SD + c);
        Tl[c + 0][r] = f2bf(v.x); Tl[c + 1][r] = f2bf(v.y);
        Tl[c + 2][r] = f2bf(v.z); Tl[c + 3][r] = f2bf(v.w);
    }
    __syncthreads();
#pragma unroll
    for (int i = 0; i < 2; ++i) {
        int f = threadIdx.x + i * 256;     // 512 ushort8 slots
        int r = f >> 3;                    // d 0..63
        int c = (f & 7) << 3;              // t-offset 0..56
        bf16x8 v = *(const bf16x8*)&Tl[r][c];
        *(bf16x8*)(Vt + ((size_t)bh * SD + r) * TS + t0 + c) = v;
    }
}

// ---------------------------------------------------------------------------
// MFMA flash attention. 4 waves/block; wave w owns q rows [qt*64+16w, +16).
// Q/K hi-lo split bf16 (S accurate to ~1e-4); V bf16; fp32 accum.
// mfma_f32_16x16x32_bf16: A[m=lane&15][k=quad*8+j], B[n=lane&15][k=quad*8+j],
// C/D: col=lane&15, row=quad*4+reg.  No __syncthreads needed (per-wave LDS).
// ---------------------------------------------------------------------------
__global__ __launch_bounds__(256)
void attn_mfma(const ushort_t* __restrict__ Qh, const ushort_t* __restrict__ Ql,
               const ushort_t* __restrict__ Kh, const ushort_t* __restrict__ Kl,
               const ushort_t* __restrict__ Vt, const int* __restrict__ mask,
               float* __restrict__ Y)
{
    const int qt = blockIdx.x;       // 0..31
    const int h  = blockIdx.y;
    const int b  = blockIdx.z;
    const int bh = b * NH + h;

    const int tid  = threadIdx.x;
    const int wave = tid >> 6;
    const int lane = tid & 63;
    const int col  = lane & 15;
    const int quad = lane >> 4;

    __shared__ ushort_t Pl[4][16][72];   // per-wave P strip [q][key], padded

    // Q fragments (held for the whole kernel)
    const int qs = qt * 64 + wave * 16;
    const ushort_t* qrow_h = Qh + ((size_t)bh * TS + qs + col) * SD;
    const ushort_t* qrow_l = Ql + ((size_t)bh * TS + qs + col) * SD;
    bf16x8 aqh[2], aql[2];
#pragma unroll
    for (int c = 0; c < 2; ++c) {
        aqh[c] = *(const bf16x8*)(qrow_h + c * 32 + quad * 8);
        aql[c] = *(const bf16x8*)(qrow_l + c * 32 + quad * 8);
    }

    float m_r[4], l_r[4];
    f32x4 O[4];
#pragma unroll
    for (int r = 0; r < 4; ++r) { m_r[r] = -INFINITY; l_r[r] = 0.f; }
#pragma unroll
    for (int dt = 0; dt < 4; ++dt) O[dt] = (f32x4){0.f, 0.f, 0.f, 0.f};

    for (int kt = 0; kt < TS / 64; ++kt) {
        // ---- S = Q K^T over this 64-key tile (hi/lo split) + mask ----
        f32x4 S[4];
#pragma unroll
        for (int nt = 0; nt < 4; ++nt) {
            const ushort_t* krow_h = Kh + ((size_t)bh * TS + kt * 64 + nt * 16 + col) * SD;
            const ushort_t* krow_l = Kl + ((size_t)bh * TS + kt * 64 + nt * 16 + col) * SD;
            f32x4 s = (f32x4){0.f, 0.f, 0.f, 0.f};
#pragma unroll
            for (int c = 0; c < 2; ++c) {
                bf16x8 bkh = *(const bf16x8*)(krow_h + c * 32 + quad * 8);
                bf16x8 bkl = *(const bf16x8*)(krow_l + c * 32 + quad * 8);
                s = __builtin_amdgcn_mfma_f32_16x16x32_bf16(aql[c], bkh, s, 0, 0, 0);
                s = __builtin_amdgcn_mfma_f32_16x16x32_bf16(aqh[c], bkl, s, 0, 0, 0);
                s = __builtin_amdgcn_mfma_f32_16x16x32_bf16(aqh[c], bkh, s, 0, 0, 0);
            }
            int mv = mask[b * TS + kt * 64 + nt * 16 + col];
            if (mv == 0) { s.x = -INFINITY; s.y = -INFINITY; s.z = -INFINITY; s.w = -INFINITY; }
            S[nt] = s;
        }
        // ---- online softmax (row = quad*4 + r; reduce across 16 cols) ----
        float tmax[4];
#pragma unroll
        for (int r = 0; r < 4; ++r)
            tmax[r] = fmaxf(fmaxf(S[0][r], S[1][r]), fmaxf(S[2][r], S[3][r]));
#pragma unroll
        for (int off = 1; off < 16; off <<= 1) {
#pragma unroll
            for (int r = 0; r < 4; ++r)
                tmax[r] = fmaxf(tmax[r], __shfl_xor(tmax[r], off));
        }
        float alpha[4], rsum[4];
#pragma unroll
        for (int r = 0; r < 4; ++r) {
            float mNew = fmaxf(m_r[r], tmax[r]);
            float mG   = (mNew == -INFINITY) ? 0.f : mNew;
            alpha[r]   = __expf(m_r[r] - mG);   // m_r=-inf -> 0; stable
            float rs = 0.f;
#pragma unroll
            for (int nt = 0; nt < 4; ++nt) {
                float p = __expf(S[nt][r] - mG);   // masked: exp(-inf)=0
                S[nt][r] = p;
                rs += p;
            }
            rsum[r] = rs;
            m_r[r]  = mNew;
        }
#pragma unroll
        for (int off = 1; off < 16; off <<= 1) {
#pragma unroll
            for (int r = 0; r < 4; ++r)
                rsum[r] += __shfl_xor(rsum[r], off);
        }
#pragma unroll
        for (int r = 0; r < 4; ++r) l_r[r] = l_r[r] * alpha[r] + rsum[r];
        // rescale O
#pragma unroll
        for (int dt = 0; dt < 4; ++dt)
#pragma unroll
            for (int r = 0; r < 4; ++r) O[dt][r] *= alpha[r];

        // ---- P: C-layout regs -> bf16 -> LDS -> A-layout frags ----
#pragma unroll
        for (int nt = 0; nt < 4; ++nt)
#pragma unroll
            for (int r = 0; r < 4; ++r)
                Pl[wave][quad * 4 + r][nt * 16 + col] = f2bf(S[nt][r]);

        bf16x8 ap[2];
#pragma unroll
        for (int c = 0; c < 2; ++c)
            ap[c] = *(const bf16x8*)&Pl[wave][col][c * 32 + quad * 8];

        // ---- O += P @ V ----
#pragma unroll
        for (int dt = 0; dt < 4; ++dt) {
            const ushort_t* vrow = Vt + ((size_t)bh * SD + dt * 16 + col) * TS + kt * 64;
#pragma unroll
            for (int c = 0; c < 2; ++c) {
                bf16x8 bv = *(const bf16x8*)(vrow + c * 32 + quad * 8);
                O[dt] = __builtin_amdgcn_mfma_f32_16x16x32_bf16(ap[c], bv, O[dt], 0, 0, 0);
            }
        }
    }

    // ---- epilogue: O / l, write Y fp32 [b][t][h*64+d] ----
    float inv[4];
#pragma unroll
    for (int r = 0; r < 4; ++r) inv[r] = 1.f / l_r[r];
#pragma unroll
    for (int dt = 0; dt < 4; ++dt)
#pragma unroll
        for (int r = 0; r < 4; ++r)
            Y[((size_t)b * TS + qs + quad * 4 + r) * KD + h * SD + dt * 16 + col] =
                O[dt][r] * inv[r];
}

// ---------------------------------------------------------------------------
extern "C" void kernel_launch(void* const* d_in, const int* in_sizes, int n_in,
                              void* d_out, int out_size, void* d_ws, size_t ws_size,
                              hipStream_t stream) {
    const float* x    = (const float*)d_in[0];
    const int*   mask = (const int*)d_in[1];
    const float* Wk   = (const float*)d_in[2];
    const float* Wq   = (const float*)d_in[3];
    const float* Wv   = (const float*)d_in[4];
    const float* Wu   = (const float*)d_in[5];
    const float* bu   = (const float*)d_in[6];
    float* out = (float*)d_out;

    char* w = (char*)d_ws;
    const size_t M16 = (size_t)16 << 20, M8 = (size_t)8 << 20;
    // overlay plan (peak 64 MB, proven size from round 0):
    float*    Qf = (float*)(w + 0);            // fp32 Q      [0,16M)
    float*    Kf = (float*)(w + M16);          // fp32 K      [16M,32M)
    float*    Vf = (float*)(w + 2 * M16);      // fp32 V      [32M,48M)
    ushort_t* QH = (ushort_t*)(w + 3 * M16);           // [48M,56M)
    ushort_t* QL = (ushort_t*)(w + 3 * M16 + M8);      // [56M,64M)
    ushort_t* KH = (ushort_t*)(w + 0);                 // over Qf (consumed)
    ushort_t* KL = (ushort_t*)(w + M8);                // [8M,16M)
    ushort_t* VT = (ushort_t*)(w + M16);               // over Kf (consumed)
    float*    Yf = (float*)(w + 2 * M16);              // over Vf (consumed)

    dim3 blk(256);
    gemm_bt<<<dim3(8, 32, 3), blk, 0, stream>>>(x, Wq, Wk, Wv, Qf, Kf, Vf, nullptr);
    conv_split<<<dim3(4096), blk, 0, stream>>>(Qf, QH, QL);
    conv_split<<<dim3(4096), blk, 0, stream>>>(Kf, KH, KL);
    conv_vt<<<dim3(32, 32), blk, 0, stream>>>(Vf, VT);
    attn_mfma<<<dim3(32, NH, 2), blk, 0, stream>>>(QH, QL, KH, KL, VT, mask, Yf);
    gemm_bt<<<dim3(8, 32, 1), blk, 0, stream>>>(Yf, Wu, nullptr, nullptr,
                                                out, nullptr, nullptr, bu);
}

// Round 3
// 555.995 us; speedup vs baseline: 1.8302x; 1.7141x over previous
//
#include <hip/hip_runtime.h>
#include <hip/hip_bf16.h>
#include <math.h>

#define TS 2048   // sequence length T
#define KD 1024   // model dim K
#define NH 16     // heads
#define SD 64     // head dim
#define MB 4096   // B*T rows

typedef __attribute__((ext_vector_type(8))) short bf16x8;   // 8 bf16 (4 VGPRs)
typedef __attribute__((ext_vector_type(4))) float f32x4;    // MFMA accumulator
typedef unsigned short ushort_t;

__device__ __forceinline__ ushort_t f2bf_rn(float f) {
    union { __hip_bfloat16 h; ushort_t u; } c;
    c.h = __float2bfloat16(f);
    return c.u;
}
__device__ __forceinline__ float bf2f(ushort_t u) {
    union { unsigned u; float f; } v; v.u = ((unsigned)u) << 16;
    return v.f;
}
__device__ __forceinline__ ushort4 pk4_bf(float a, float b, float c, float d) {
    union { __hip_bfloat162 h; ushort2 u; } x, y;
    x.h = __float22bfloat162_rn(make_float2(a, b));
    y.h = __float22bfloat162_rn(make_float2(c, d));
    return make_ushort4(x.u.x, x.u.y, y.u.x, y.u.y);
}
// async global -> LDS, 16 B per lane; lds ptr must be wave-uniform
__device__ __forceinline__ void gload_lds16(const void* g, void* l) {
    __builtin_amdgcn_global_load_lds(
        (const __attribute__((address_space(1))) unsigned int*)g,
        (__attribute__((address_space(3))) unsigned int*)l, 16, 0, 0);
}

// ---------------------------------------------------------------------------
// conv_all: z=0: x -> XH,XL (hi/lo bf16); z=1: Wq -> hi/lo; z=2: Wk -> hi/lo;
// z=3: Wv -> hi; z=4: Wu -> hi.
// ---------------------------------------------------------------------------
__global__ __launch_bounds__(256)
void conv_all(const float* __restrict__ x, const float* __restrict__ wq,
              const float* __restrict__ wk, const float* __restrict__ wv,
              const float* __restrict__ wu,
              ushort_t* XH, ushort_t* XL, ushort_t* WqH, ushort_t* WqL,
              ushort_t* WkH, ushort_t* WkL, ushort_t* WvH, ushort_t* WuH)
{
    int z = blockIdx.y;
    const float* src; ushort_t* H; ushort_t* L = nullptr; int nblk;
    switch (z) {
        case 0:  src = x;  H = XH;  L = XL;  nblk = 4096; break;
        case 1:  src = wq; H = WqH; L = WqL; nblk = 1024; break;
        case 2:  src = wk; H = WkH; L = WkL; nblk = 1024; break;
        case 3:  src = wv; H = WvH;          nblk = 1024; break;
        default: src = wu; H = WuH;          nblk = 1024; break;
    }
    if ((int)blockIdx.x >= nblk) return;
    int idx = blockIdx.x * 256 + threadIdx.x;      // float4 index
    float4 v = ((const float4*)src)[idx];
    ushort_t h0 = f2bf_rn(v.x), h1 = f2bf_rn(v.y);
    ushort_t h2 = f2bf_rn(v.z), h3 = f2bf_rn(v.w);
    ((ushort4*)H)[idx] = make_ushort4(h0, h1, h2, h3);
    if (L) {
        ushort_t l0 = f2bf_rn(v.x - bf2f(h0)), l1 = f2bf_rn(v.y - bf2f(h1));
        ushort_t l2 = f2bf_rn(v.z - bf2f(h2)), l3 = f2bf_rn(v.w - bf2f(h3));
        ((ushort4*)L)[idx] = make_ushort4(l0, l1, l2, l3);
    }
}

// ---------------------------------------------------------------------------
// MFMA GEMM: C = A @ W^T. 128x128 tile, BK=32, 4 waves (2x2), 64x64/wave.
// A, W stored as bf16 hi(/lo) row-major [rows][1024]. terms3 = hi/lo split
// (3 MFMA per product term). Epilogues:
//   epi 0/1: write hi/lo bf16 [4096][1024] (Q / K)
//   epi 2  : write transposed bf16 Vt[b*NH+h][d][t]
//   epi 3  : write fp32 + bias (final output)
// ---------------------------------------------------------------------------
__global__ __launch_bounds__(256)
void gemm_bf16(const ushort_t* __restrict__ Ah, const ushort_t* __restrict__ Al,
               const ushort_t* __restrict__ Bqh, const ushort_t* __restrict__ Bql,
               const ushort_t* __restrict__ Bkh, const ushort_t* __restrict__ Bkl,
               const ushort_t* __restrict__ Bvh, const ushort_t* __restrict__ Buh,
               ushort_t* __restrict__ OQh, ushort_t* __restrict__ OQl,
               ushort_t* __restrict__ OKh, ushort_t* __restrict__ OKl,
               ushort_t* __restrict__ OVt, float* __restrict__ OF,
               const float* __restrict__ bias, int epi_base)
{
    const int epi = epi_base + blockIdx.z;
    const ushort_t* Bh; const ushort_t* Bl = nullptr;
    if      (epi == 0) { Bh = Bqh; Bl = Bql; }
    else if (epi == 1) { Bh = Bkh; Bl = Bkl; }
    else if (epi == 2) { Bh = Bvh; }
    else               { Bh = Buh; }
    const bool terms3 = (epi < 2);

    __shared__ ushort_t sAh[128 * 32];
    __shared__ ushort_t sAl[128 * 32];
    __shared__ ushort_t sBh[128 * 32];
    __shared__ ushort_t sBl[128 * 32];

    const int tid = threadIdx.x;
    const int wave = tid >> 6, lane = tid & 63;
    const int col = lane & 15, quad = lane >> 4;
    const int wm = wave >> 1, wn = wave & 1;
    const int m0 = blockIdx.y * 128, n0 = blockIdx.x * 128;

    f32x4 acc[4][4];
#pragma unroll
    for (int i = 0; i < 4; ++i)
#pragma unroll
        for (int j = 0; j < 4; ++j) acc[i][j] = (f32x4){0.f, 0.f, 0.f, 0.f};

    for (int k0 = 0; k0 < KD; k0 += 32) {
#pragma unroll
        for (int j = 0; j < 2; ++j) {
            int s   = wave * 128 + j * 64 + lane;   // 16B-slot index
            int row = s >> 2, k8 = s & 3;
            int lo  = (wave * 128 + j * 64) * 8;    // ushort units, wave-uniform
            gload_lds16(Ah + (size_t)(m0 + row) * KD + k0 + k8 * 8, sAh + lo);
            gload_lds16(Bh + (size_t)(n0 + row) * KD + k0 + k8 * 8, sBh + lo);
            if (terms3) {
                gload_lds16(Al + (size_t)(m0 + row) * KD + k0 + k8 * 8, sAl + lo);
                gload_lds16(Bl + (size_t)(n0 + row) * KD + k0 + k8 * 8, sBl + lo);
            }
        }
        __syncthreads();

        bf16x8 fbh[4], fbl[4];
#pragma unroll
        for (int j = 0; j < 4; ++j) {
            int r = (wn * 64 + j * 16 + col) * 32 + quad * 8;
            fbh[j] = *(const bf16x8*)&sBh[r];
            if (terms3) fbl[j] = *(const bf16x8*)&sBl[r];
        }
#pragma unroll
        for (int i = 0; i < 4; ++i) {
            int r = (wm * 64 + i * 16 + col) * 32 + quad * 8;
            bf16x8 fah = *(const bf16x8*)&sAh[r];
            if (terms3) {
                bf16x8 fal = *(const bf16x8*)&sAl[r];
#pragma unroll
                for (int j = 0; j < 4; ++j) {
                    acc[i][j] = __builtin_amdgcn_mfma_f32_16x16x32_bf16(fah, fbh[j], acc[i][j], 0, 0, 0);
                    acc[i][j] = __builtin_amdgcn_mfma_f32_16x16x32_bf16(fah, fbl[j], acc[i][j], 0, 0, 0);
                    acc[i][j] = __builtin_amdgcn_mfma_f32_16x16x32_bf16(fal, fbh[j], acc[i][j], 0, 0, 0);
                }
            } else {
#pragma unroll
                for (int j = 0; j < 4; ++j)
                    acc[i][j] = __builtin_amdgcn_mfma_f32_16x16x32_bf16(fah, fbh[j], acc[i][j], 0, 0, 0);
            }
        }
        __syncthreads();
    }

    // ---- epilogues (C/D: row m = quad*4+reg, col n = lane&15) ----
    if (epi <= 1) {
        ushort_t* OH = (epi == 0) ? OQh : OKh;
        ushort_t* OL = (epi == 0) ? OQl : OKl;
#pragma unroll
        for (int i = 0; i < 4; ++i) {
            int m = m0 + wm * 64 + i * 16 + quad * 4;
#pragma unroll
            for (int j = 0; j < 4; ++j) {
                int n = n0 + wn * 64 + j * 16 + col;
#pragma unroll
                for (int r = 0; r < 4; ++r) {
                    float v = acc[i][j][r];
                    ushort_t hv = f2bf_rn(v);
                    size_t off = (size_t)(m + r) * KD + n;
                    OH[off] = hv;
                    OL[off] = f2bf_rn(v - bf2f(hv));
                }
            }
        }
    } else if (epi == 2) {
#pragma unroll
        for (int i = 0; i < 4; ++i) {
            int m = m0 + wm * 64 + i * 16 + quad * 4;
            int bb = m >> 11, t = m & (TS - 1);
#pragma unroll
            for (int j = 0; j < 4; ++j) {
                int n = n0 + wn * 64 + j * 16 + col;
                int hh = n >> 6, d = n & 63;
                ushort4 pk = pk4_bf(acc[i][j][0], acc[i][j][1], acc[i][j][2], acc[i][j][3]);
                *(ushort4*)(OVt + ((size_t)(bb * NH + hh) * SD + d) * TS + t) = pk;
            }
        }
    } else {
#pragma unroll
        for (int i = 0; i < 4; ++i) {
            int m = m0 + wm * 64 + i * 16 + quad * 4;
#pragma unroll
            for (int j = 0; j < 4; ++j) {
                int n = n0 + wn * 64 + j * 16 + col;
                float bj = bias[n];
#pragma unroll
                for (int r = 0; r < 4; ++r)
                    OF[(size_t)(m + r) * KD + n] = acc[i][j][r] + bj;
            }
        }
    }
}

// ---------------------------------------------------------------------------
// MFMA flash attention, no-max softmax (logits bounded; exp(S) fits fp32).
// S^T form: A=K (rows=key), B=Q (cols=q) -> P lands with q=col, key=row.
// P -> LDS (4x ds_write_b64) -> A-frag (2x ds_read_b128) -> O += P @ V^T.
// l accumulated as per-lane scalar; one shuffle-reduce at the end.
// Per-wave LDS strip: no __syncthreads anywhere.
// ---------------------------------------------------------------------------
__global__ __launch_bounds__(256)
void attn_mfma(const ushort_t* __restrict__ QH, const ushort_t* __restrict__ QL,
               const ushort_t* __restrict__ KH, const ushort_t* __restrict__ KL,
               const ushort_t* __restrict__ VT, const int* __restrict__ mask,
               ushort_t* __restrict__ YH)
{
    const int qt = blockIdx.x;       // 0..31
    const int h  = blockIdx.y;
    const int b  = blockIdx.z;

    const int tid  = threadIdx.x;
    const int wave = tid >> 6;
    const int lane = tid & 63;
    const int col  = lane & 15;
    const int quad = lane >> 4;

    __shared__ ushort_t Pl[4][16][72];   // [wave][q][key], stride 72 (16B rows)

    const int qs = qt * 64 + wave * 16;
    const ushort_t* qh_p = QH + (size_t)(b * TS + qs + col) * KD + h * SD;
    const ushort_t* ql_p = QL + (size_t)(b * TS + qs + col) * KD + h * SD;
    bf16x8 bqh[2], bql[2];
#pragma unroll
    for (int c = 0; c < 2; ++c) {
        bqh[c] = *(const bf16x8*)(qh_p + c * 32 + quad * 8);
        bql[c] = *(const bf16x8*)(ql_p + c * 32 + quad * 8);
    }

    float lp = 0.f;
    f32x4 O[4];
#pragma unroll
    for (int dt = 0; dt < 4; ++dt) O[dt] = (f32x4){0.f, 0.f, 0.f, 0.f};

    for (int kt = 0; kt < TS / 64; ++kt) {
        const int kbase = kt * 64;
        // ---- S^T = K Q^T (hi/lo split, 3 MFMA per 16x16x32) ----
        f32x4 S[4];
#pragma unroll
        for (int nt = 0; nt < 4; ++nt) {
            const size_t krow = (size_t)(b * TS + kbase + nt * 16 + col) * KD + h * SD;
            f32x4 s = (f32x4){0.f, 0.f, 0.f, 0.f};
#pragma unroll
            for (int c = 0; c < 2; ++c) {
                bf16x8 akh = *(const bf16x8*)(KH + krow + c * 32 + quad * 8);
                bf16x8 akl = *(const bf16x8*)(KL + krow + c * 32 + quad * 8);
                s = __builtin_amdgcn_mfma_f32_16x16x32_bf16(akl, bqh[c], s, 0, 0, 0);
                s = __builtin_amdgcn_mfma_f32_16x16x32_bf16(akh, bql[c], s, 0, 0, 0);
                s = __builtin_amdgcn_mfma_f32_16x16x32_bf16(akh, bqh[c], s, 0, 0, 0);
            }
            S[nt] = s;
        }
        // ---- P = mask ? exp(S) : 0 ; accumulate l partial; store P to LDS ----
#pragma unroll
        for (int nt = 0; nt < 4; ++nt) {
            int4 mv = *(const int4*)(mask + b * TS + kbase + nt * 16 + quad * 4);
            float p0 = mv.x ? __expf(S[nt][0]) : 0.f;
            float p1 = mv.y ? __expf(S[nt][1]) : 0.f;
            float p2 = mv.z ? __expf(S[nt][2]) : 0.f;
            float p3 = mv.w ? __expf(S[nt][3]) : 0.f;
            lp += (p0 + p1) + (p2 + p3);
            *(ushort4*)&Pl[wave][col][nt * 16 + quad * 4] = pk4_bf(p0, p1, p2, p3);
        }
        // ---- P A-frags ----
        bf16x8 ap0 = *(const bf16x8*)&Pl[wave][col][quad * 8];
        bf16x8 ap1 = *(const bf16x8*)&Pl[wave][col][32 + quad * 8];
        // ---- O += P @ V^T ----
#pragma unroll
        for (int dt = 0; dt < 4; ++dt) {
            const size_t vrow = ((size_t)(b * NH + h) * SD + dt * 16 + col) * TS + kbase;
            bf16x8 bv0 = *(const bf16x8*)(VT + vrow + quad * 8);
            bf16x8 bv1 = *(const bf16x8*)(VT + vrow + 32 + quad * 8);
            O[dt] = __builtin_amdgcn_mfma_f32_16x16x32_bf16(ap0, bv0, O[dt], 0, 0, 0);
            O[dt] = __builtin_amdgcn_mfma_f32_16x16x32_bf16(ap1, bv1, O[dt], 0, 0, 0);
        }
    }

    // ---- final l reduce + epilogue (bf16 Y for the U projection) ----
    lp += __shfl_xor(lp, 16);
    lp += __shfl_xor(lp, 32);
    float linv[4];
#pragma unroll
    for (int r = 0; r < 4; ++r) linv[r] = 1.f / __shfl(lp, quad * 4 + r);
#pragma unroll
    for (int dt = 0; dt < 4; ++dt)
#pragma unroll
        for (int r = 0; r < 4; ++r)
            YH[(size_t)(b * TS + qs + quad * 4 + r) * KD + h * SD + dt * 16 + col] =
                f2bf_rn(O[dt][r] * linv[r]);
}

// ---------------------------------------------------------------------------
extern "C" void kernel_launch(void* const* d_in, const int* in_sizes, int n_in,
                              void* d_out, int out_size, void* d_ws, size_t ws_size,
                              hipStream_t stream) {
    const float* x    = (const float*)d_in[0];
    const int*   mask = (const int*)d_in[1];
    const float* Wk   = (const float*)d_in[2];
    const float* Wq   = (const float*)d_in[3];
    const float* Wv   = (const float*)d_in[4];
    const float* Wu   = (const float*)d_in[5];
    const float* bu   = (const float*)d_in[6];
    float* out = (float*)d_out;

    char* w = (char*)d_ws;
    const size_t M1 = (size_t)1 << 20;
    // overlay plan, peak 60 MB:
    ushort_t* XH  = (ushort_t*)(w);              // [0,8M)   x hi
    ushort_t* XL  = (ushort_t*)(w + 8  * M1);    // [8,16M)  x lo
    ushort_t* WqH = (ushort_t*)(w + 16 * M1);    // [16,18M)
    ushort_t* WqL = (ushort_t*)(w + 18 * M1);
    ushort_t* WkH = (ushort_t*)(w + 20 * M1);
    ushort_t* WkL = (ushort_t*)(w + 22 * M1);
    ushort_t* WvH = (ushort_t*)(w + 24 * M1);
    ushort_t* WuH = (ushort_t*)(w + 26 * M1);
    ushort_t* QHb = (ushort_t*)(w + 28 * M1);    // [28,36M)
    ushort_t* QLb = (ushort_t*)(w + 36 * M1);
    ushort_t* KHb = (ushort_t*)(w + 44 * M1);
    ushort_t* KLb = (ushort_t*)(w + 52 * M1);    // ..60M
    ushort_t* VTb = (ushort_t*)(w + 16 * M1);    // over Wq/Wk hi/lo (dead after QK gemm)
    ushort_t* YHb = (ushort_t*)(w);              // over XH (dead after V gemm)

    dim3 blk(256);
    conv_all<<<dim3(4096, 5), blk, 0, stream>>>(x, Wq, Wk, Wv, Wu,
                                                XH, XL, WqH, WqL, WkH, WkL, WvH, WuH);
    // Q and K projections (3-term hi/lo split), fused epilogue -> hi/lo bf16
    gemm_bf16<<<dim3(8, 32, 2), blk, 0, stream>>>(XH, XL, WqH, WqL, WkH, WkL, WvH, WuH,
                                                  QHb, QLb, KHb, KLb, nullptr, nullptr,
                                                  nullptr, 0);
    // V projection (1-term), epilogue -> transposed Vt (overlays Wq/Wk)
    gemm_bf16<<<dim3(8, 32, 1), blk, 0, stream>>>(XH, XL, WqH, WqL, WkH, WkL, WvH, WuH,
                                                  nullptr, nullptr, nullptr, nullptr, VTb,
                                                  nullptr, nullptr, 2);
    // attention -> bf16 Y (overlays XH)
    attn_mfma<<<dim3(32, NH, 2), blk, 0, stream>>>(QHb, QLb, KHb, KLb, VTb, mask, YHb);
    // output projection (1-term) + bias -> fp32 out
    gemm_bf16<<<dim3(8, 32, 1), blk, 0, stream>>>(YHb, nullptr, WqH, WqL, WkH, WkL, WvH, WuH,
                                                  nullptr, nullptr, nullptr, nullptr, nullptr,
                                                  out, bu, 3);
}

// Round 5
// 318.075 us; speedup vs baseline: 3.1992x; 1.7480x over previous
//
#include <hip/hip_runtime.h>
#include <hip/hip_bf16.h>
#include <math.h>

#define TS 2048   // sequence length T
#define KD 1024   // model dim K
#define NH 16     // heads
#define SD 64     // head dim
#define MB 4096   // B*T rows
#define LOG2E 1.4426950408889634f

typedef __attribute__((ext_vector_type(8))) short bf16x8;   // 8 bf16 (4 VGPRs)
typedef __attribute__((ext_vector_type(4))) short bf16x4;   // 4 bf16 (2 VGPRs)
typedef __attribute__((ext_vector_type(4))) float f32x4;    // MFMA accumulator
typedef unsigned short ushort_t;

#define MFMA32(a, b, c) __builtin_amdgcn_mfma_f32_16x16x32_bf16(a, b, c, 0, 0, 0)

__device__ __forceinline__ ushort_t f2bf_rn(float f) {
    union { __hip_bfloat16 h; ushort_t u; } c;
    c.h = __float2bfloat16(f);
    return c.u;
}
__device__ __forceinline__ float bf2f(ushort_t u) {
    union { unsigned u; float f; } v; v.u = ((unsigned)u) << 16;
    return v.f;
}
__device__ __forceinline__ ushort4 pk4_bf(float a, float b, float c, float d) {
    union { __hip_bfloat162 h; ushort2 u; } x, y;
    x.h = __float22bfloat162_rn(make_float2(a, b));
    y.h = __float22bfloat162_rn(make_float2(c, d));
    return make_ushort4(x.u.x, x.u.y, y.u.x, y.u.y);
}
// async global -> LDS, 16 B per lane; lds ptr must be wave-uniform
__device__ __forceinline__ void gload_lds16(const void* g, void* l) {
    __builtin_amdgcn_global_load_lds(
        (const __attribute__((address_space(1))) unsigned int*)g,
        (__attribute__((address_space(3))) unsigned int*)l, 16, 0, 0);
}

// ---------------------------------------------------------------------------
// conv_all: z=0: x -> XH,XL (hi/lo); z=1: Wq*log2e -> hi/lo (folds exp->exp2);
// z=2: Wk -> hi/lo; z=3: Wv -> hi; z=4: Wu -> hi.
// ---------------------------------------------------------------------------
__global__ __launch_bounds__(256)
void conv_all(const float* __restrict__ x, const float* __restrict__ wq,
              const float* __restrict__ wk, const float* __restrict__ wv,
              const float* __restrict__ wu,
              ushort_t* XH, ushort_t* XL, ushort_t* WqH, ushort_t* WqL,
              ushort_t* WkH, ushort_t* WkL, ushort_t* WvH, ushort_t* WuH)
{
    int z = blockIdx.y;
    const float* src; ushort_t* H; ushort_t* L = nullptr; int nblk;
    switch (z) {
        case 0:  src = x;  H = XH;  L = XL;  nblk = 4096; break;
        case 1:  src = wq; H = WqH; L = WqL; nblk = 1024; break;
        case 2:  src = wk; H = WkH; L = WkL; nblk = 1024; break;
        case 3:  src = wv; H = WvH;          nblk = 1024; break;
        default: src = wu; H = WuH;          nblk = 1024; break;
    }
    if ((int)blockIdx.x >= nblk) return;
    int idx = blockIdx.x * 256 + threadIdx.x;      // float4 index
    float4 v = ((const float4*)src)[idx];
    if (z == 1) { v.x *= LOG2E; v.y *= LOG2E; v.z *= LOG2E; v.w *= LOG2E; }
    ushort_t h0 = f2bf_rn(v.x), h1 = f2bf_rn(v.y);
    ushort_t h2 = f2bf_rn(v.z), h3 = f2bf_rn(v.w);
    ((ushort4*)H)[idx] = make_ushort4(h0, h1, h2, h3);
    if (L) {
        ushort_t l0 = f2bf_rn(v.x - bf2f(h0)), l1 = f2bf_rn(v.y - bf2f(h1));
        ushort_t l2 = f2bf_rn(v.z - bf2f(h2)), l3 = f2bf_rn(v.w - bf2f(h3));
        ((ushort4*)L)[idx] = make_ushort4(l0, l1, l2, l3);
    }
}

// ---------------------------------------------------------------------------
// MFMA GEMM: C = A @ W^T. 128x128 tile, BK=32, 4 waves (2x2), 64x64/wave.
// (unchanged — known good)
// ---------------------------------------------------------------------------
__global__ __launch_bounds__(256)
void gemm_bf16(const ushort_t* __restrict__ Ah, const ushort_t* __restrict__ Al,
               const ushort_t* __restrict__ Bqh, const ushort_t* __restrict__ Bql,
               const ushort_t* __restrict__ Bkh, const ushort_t* __restrict__ Bkl,
               const ushort_t* __restrict__ Bvh, const ushort_t* __restrict__ Buh,
               ushort_t* __restrict__ OQh, ushort_t* __restrict__ OQl,
               ushort_t* __restrict__ OKh, ushort_t* __restrict__ OKl,
               ushort_t* __restrict__ OVt, float* __restrict__ OF,
               const float* __restrict__ bias, int epi_base)
{
    const int epi = epi_base + blockIdx.z;
    const ushort_t* Bh; const ushort_t* Bl = nullptr;
    if      (epi == 0) { Bh = Bqh; Bl = Bql; }
    else if (epi == 1) { Bh = Bkh; Bl = Bkl; }
    else if (epi == 2) { Bh = Bvh; }
    else               { Bh = Buh; }
    const bool terms3 = (epi < 2);

    __shared__ ushort_t sAh[128 * 32];
    __shared__ ushort_t sAl[128 * 32];
    __shared__ ushort_t sBh[128 * 32];
    __shared__ ushort_t sBl[128 * 32];

    const int tid = threadIdx.x;
    const int wave = tid >> 6, lane = tid & 63;
    const int col = lane & 15, quad = lane >> 4;
    const int wm = wave >> 1, wn = wave & 1;
    const int m0 = blockIdx.y * 128, n0 = blockIdx.x * 128;

    f32x4 acc[4][4];
#pragma unroll
    for (int i = 0; i < 4; ++i)
#pragma unroll
        for (int j = 0; j < 4; ++j) acc[i][j] = (f32x4){0.f, 0.f, 0.f, 0.f};

    for (int k0 = 0; k0 < KD; k0 += 32) {
#pragma unroll
        for (int j = 0; j < 2; ++j) {
            int s   = wave * 128 + j * 64 + lane;   // 16B-slot index
            int row = s >> 2, k8 = s & 3;
            int lo  = (wave * 128 + j * 64) * 8;    // ushort units, wave-uniform
            gload_lds16(Ah + (size_t)(m0 + row) * KD + k0 + k8 * 8, sAh + lo);
            gload_lds16(Bh + (size_t)(n0 + row) * KD + k0 + k8 * 8, sBh + lo);
            if (terms3) {
                gload_lds16(Al + (size_t)(m0 + row) * KD + k0 + k8 * 8, sAl + lo);
                gload_lds16(Bl + (size_t)(n0 + row) * KD + k0 + k8 * 8, sBl + lo);
            }
        }
        __syncthreads();

        bf16x8 fbh[4], fbl[4];
#pragma unroll
        for (int j = 0; j < 4; ++j) {
            int r = (wn * 64 + j * 16 + col) * 32 + quad * 8;
            fbh[j] = *(const bf16x8*)&sBh[r];
            if (terms3) fbl[j] = *(const bf16x8*)&sBl[r];
        }
#pragma unroll
        for (int i = 0; i < 4; ++i) {
            int r = (wm * 64 + i * 16 + col) * 32 + quad * 8;
            bf16x8 fah = *(const bf16x8*)&sAh[r];
            if (terms3) {
                bf16x8 fal = *(const bf16x8*)&sAl[r];
#pragma unroll
                for (int j = 0; j < 4; ++j) {
                    acc[i][j] = MFMA32(fah, fbh[j], acc[i][j]);
                    acc[i][j] = MFMA32(fah, fbl[j], acc[i][j]);
                    acc[i][j] = MFMA32(fal, fbh[j], acc[i][j]);
                }
            } else {
#pragma unroll
                for (int j = 0; j < 4; ++j)
                    acc[i][j] = MFMA32(fah, fbh[j], acc[i][j]);
            }
        }
        __syncthreads();
    }

    if (epi <= 1) {
        ushort_t* OH = (epi == 0) ? OQh : OKh;
        ushort_t* OL = (epi == 0) ? OQl : OKl;
#pragma unroll
        for (int i = 0; i < 4; ++i) {
            int m = m0 + wm * 64 + i * 16 + quad * 4;
#pragma unroll
            for (int j = 0; j < 4; ++j) {
                int n = n0 + wn * 64 + j * 16 + col;
#pragma unroll
                for (int r = 0; r < 4; ++r) {
                    float v = acc[i][j][r];
                    ushort_t hv = f2bf_rn(v);
                    size_t off = (size_t)(m + r) * KD + n;
                    OH[off] = hv;
                    OL[off] = f2bf_rn(v - bf2f(hv));
                }
            }
        }
    } else if (epi == 2) {
#pragma unroll
        for (int i = 0; i < 4; ++i) {
            int m = m0 + wm * 64 + i * 16 + quad * 4;
            int bb = m >> 11, t = m & (TS - 1);
#pragma unroll
            for (int j = 0; j < 4; ++j) {
                int n = n0 + wn * 64 + j * 16 + col;
                int hh = n >> 6, d = n & 63;
                ushort4 pk = pk4_bf(acc[i][j][0], acc[i][j][1], acc[i][j][2], acc[i][j][3]);
                *(ushort4*)(OVt + ((size_t)(bb * NH + hh) * SD + d) * TS + t) = pk;
            }
        }
    } else {
#pragma unroll
        for (int i = 0; i < 4; ++i) {
            int m = m0 + wm * 64 + i * 16 + quad * 4;
#pragma unroll
            for (int j = 0; j < 4; ++j) {
                int n = n0 + wn * 64 + j * 16 + col;
                float bj = bias[n];
#pragma unroll
                for (int r = 0; r < 4; ++r)
                    OF[(size_t)(m + r) * KD + n] = acc[i][j][r] + bj;
            }
        }
    }
}

// ---------------------------------------------------------------------------
// MFMA flash attention, keys distributed across waves.
// Block = (64 q) x (b,h). Wave w owns keys [kt*64 + w*16, +16) each kt, ALL q.
// K hi/lo + V^T staged once per block per kt into XOR-swizzled LDS (each byte
// read exactly once).  S^T = K·Q^T via 16x16x32 (3-term hi/lo, 2 indep chains).
// P = exp2(S') stays in registers: S^T's C-layout [key=quad*4+r][q=col] maps
// to k-slots quad*8+{0..3} of a zero-padded 16x16x32 B-operand; the V^T
// A-operand uses the same key mapping (upper half zeroed — NOT garbage, since
// garbage*0 = NaN in MFMA).  No running max (logits bounded).
// Cross-wave O/l reduction once at the end.
// ---------------------------------------------------------------------------
__global__ __launch_bounds__(256, 2)
void attn_mfma(const ushort_t* __restrict__ QH, const ushort_t* __restrict__ QL,
               const ushort_t* __restrict__ KH, const ushort_t* __restrict__ KL,
               const ushort_t* __restrict__ VT, const int* __restrict__ mask,
               ushort_t* __restrict__ YH)
{
    const int qt = blockIdx.x;       // 0..31
    const int h  = blockIdx.y;
    const int b  = blockIdx.z;
    const int bh = b * NH + h;

    const int tid  = threadIdx.x;
    const int wave = tid >> 6;
    const int lane = tid & 63;
    const int col  = lane & 15;
    const int quad = lane >> 4;

    __shared__ ushort_t smem[24576];     // 48 KB: staging (24 KB) / O-reduce (48 KB)
    ushort_t* sKH = smem;                // [key][d] swizzled, 8 KB
    ushort_t* sKL = smem + 4096;
    ushort_t* sVT = smem + 8192;         // [d][key] swizzled, 8 KB
    __shared__ float lred[4][64];

    // ---- Q fragments, held in registers for the whole kernel ----
    bf16x8 bqh[4][2], bql[4][2];
#pragma unroll
    for (int qf = 0; qf < 4; ++qf) {
        size_t qrow = (size_t)(b * TS + qt * 64 + qf * 16 + col) * KD + h * SD;
#pragma unroll
        for (int c = 0; c < 2; ++c) {
            bqh[qf][c] = *(const bf16x8*)(QH + qrow + c * 32 + quad * 8);
            bql[qf][c] = *(const bf16x8*)(QL + qrow + c * 32 + quad * 8);
        }
    }

    float lp[4] = {0.f, 0.f, 0.f, 0.f};
    f32x4 O[4][4];                        // [dt][qf], O^T: row=d, col=q
#pragma unroll
    for (int dt = 0; dt < 4; ++dt)
#pragma unroll
        for (int qf = 0; qf < 4; ++qf) O[dt][qf] = (f32x4){0.f, 0.f, 0.f, 0.f};

    const int l8 = lane >> 3, l7 = lane & 7;

    for (int kt = 0; kt < TS / 64; ++kt) {
        const int kb = kt * 64;
        // ---- stage K hi/lo + V^T (24 KB), XOR-swizzled 16B slots ----
#pragma unroll
        for (int r = 0; r < 6; ++r) {
            int c = r * 4 + wave;                 // 1 KB chunk 0..23
            if (c < 8) {                          // KH rows 8c..8c+7
                int row = c * 8 + l8;
                int gs  = l7 ^ (row & 7);
                gload_lds16(KH + (size_t)(b * TS + kb + row) * KD + h * SD + gs * 8,
                            sKH + c * 512);
            } else if (c < 16) {                  // KL
                int cc = c - 8, row = cc * 8 + l8;
                int gs = l7 ^ (row & 7);
                gload_lds16(KL + (size_t)(b * TS + kb + row) * KD + h * SD + gs * 8,
                            sKL + cc * 512);
            } else {                              // VT rows d = 8cc..
                int cc = c - 16, row = cc * 8 + l8;
                int gs = l7 ^ (row & 7);
                gload_lds16(VT + ((size_t)bh * SD + row) * TS + kb + gs * 8,
                            sVT + cc * 512);
            }
        }
        int4 mv = *(const int4*)(mask + b * TS + kb + wave * 16 + quad * 4);
        __syncthreads();

        // ---- K fragments for this wave's 16-key strip (shared by all qf) ----
        bf16x8 akh[2], akl[2];
#pragma unroll
        for (int c = 0; c < 2; ++c) {
            int sl = (c * 4 + quad) ^ (col & 7);
            akh[c] = *(const bf16x8*)&sKH[((wave * 16 + col) * 8 + sl) * 8];
            akl[c] = *(const bf16x8*)&sKL[((wave * 16 + col) * 8 + sl) * 8];
        }
        // V^T fragments: keys wave*16+quad*4+{0..3} in k-slots quad*8+{0..3},
        // upper half zero (must be zero, not garbage: garbage*0 = NaN).
        bf16x8 av[4];
#pragma unroll
        for (int dt = 0; dt < 4; ++dt) {
            int sl = (wave * 2 + (quad >> 1)) ^ (col & 7);
            bf16x4 v4 = *(const bf16x4*)&sVT[((dt * 16 + col) * 8 + sl) * 8 + (quad & 1) * 4];
            av[dt] = (bf16x8){v4[0], v4[1], v4[2], v4[3], 0, 0, 0, 0};
        }

        // ---- S^T strips + exp2 + pack P (zero-padded B-operand) ----
        bf16x8 bp[4];
#pragma unroll
        for (int qf = 0; qf < 4; ++qf) {
            f32x4 s1 = (f32x4){0.f, 0.f, 0.f, 0.f};
            f32x4 s2 = (f32x4){0.f, 0.f, 0.f, 0.f};
            s1 = MFMA32(akh[0], bqh[qf][0], s1);
            s2 = MFMA32(akl[0], bqh[qf][0], s2);
            s2 = MFMA32(akh[0], bql[qf][0], s2);
            s1 = MFMA32(akh[1], bqh[qf][1], s1);
            s2 = MFMA32(akl[1], bqh[qf][1], s2);
            s2 = MFMA32(akh[1], bql[qf][1], s2);
            float p0 = mv.x ? exp2f(s1[0] + s2[0]) : 0.f;
            float p1 = mv.y ? exp2f(s1[1] + s2[1]) : 0.f;
            float p2 = mv.z ? exp2f(s1[2] + s2[2]) : 0.f;
            float p3 = mv.w ? exp2f(s1[3] + s2[3]) : 0.f;
            lp[qf] += (p0 + p1) + (p2 + p3);
            union { ushort4 u4; bf16x4 v4; } pk;
            pk.u4 = pk4_bf(p0, p1, p2, p3);
            bp[qf] = (bf16x8){pk.v4[0], pk.v4[1], pk.v4[2], pk.v4[3], 0, 0, 0, 0};
        }

        // ---- O^T += V^T x P^T (zero-padded K=32 MFMA, P direct from regs) ----
#pragma unroll
        for (int dt = 0; dt < 4; ++dt)
#pragma unroll
            for (int qf = 0; qf < 4; ++qf)
                O[dt][qf] = MFMA32(av[dt], bp[qf], O[dt][qf]);

        __syncthreads();
    }

    // ---- reduce l over quads (wave-local) ----
    float lq[4];
#pragma unroll
    for (int qf = 0; qf < 4; ++qf) {
        float v = lp[qf];
        v += __shfl_xor(v, 16);
        v += __shfl_xor(v, 32);
        lq[qf] = v;
    }
    if (lane < 16) {
#pragma unroll
        for (int qf = 0; qf < 4; ++qf) lred[wave][qf * 16 + lane] = lq[qf];
    }
    // ---- waves 1..3 dump O; wave 0 accumulates + epilogue ----
    float* Ored = (float*)smem;          // 3 x 4096 floats
    if (wave > 0) {
        float* dst = Ored + (wave - 1) * 4096;
#pragma unroll
        for (int dt = 0; dt < 4; ++dt)
#pragma unroll
            for (int qf = 0; qf < 4; ++qf)
                *(f32x4*)&dst[((dt * 4 + qf) * 64 + lane) * 4] = O[dt][qf];
    }
    __syncthreads();
    if (wave == 0) {
#pragma unroll
        for (int w = 0; w < 3; ++w)
#pragma unroll
            for (int dt = 0; dt < 4; ++dt)
#pragma unroll
                for (int qf = 0; qf < 4; ++qf) {
                    f32x4 t = *(const f32x4*)&Ored[w * 4096 + ((dt * 4 + qf) * 64 + lane) * 4];
                    O[dt][qf] += t;
                }
        float linv[4];
#pragma unroll
        for (int qf = 0; qf < 4; ++qf) {
            int q = qf * 16 + col;
            linv[qf] = 1.f / (lred[0][q] + lred[1][q] + lred[2][q] + lred[3][q]);
        }
#pragma unroll
        for (int dt = 0; dt < 4; ++dt)
#pragma unroll
            for (int qf = 0; qf < 4; ++qf) {
                ushort4 pk = pk4_bf(O[dt][qf][0] * linv[qf], O[dt][qf][1] * linv[qf],
                                    O[dt][qf][2] * linv[qf], O[dt][qf][3] * linv[qf]);
                *(ushort4*)(YH + (size_t)(b * TS + qt * 64 + qf * 16 + col) * KD +
                            h * SD + dt * 16 + quad * 4) = pk;
            }
    }
}

// ---------------------------------------------------------------------------
extern "C" void kernel_launch(void* const* d_in, const int* in_sizes, int n_in,
                              void* d_out, int out_size, void* d_ws, size_t ws_size,
                              hipStream_t stream) {
    const float* x    = (const float*)d_in[0];
    const int*   mask = (const int*)d_in[1];
    const float* Wk   = (const float*)d_in[2];
    const float* Wq   = (const float*)d_in[3];
    const float* Wv   = (const float*)d_in[4];
    const float* Wu   = (const float*)d_in[5];
    const float* bu   = (const float*)d_in[6];
    float* out = (float*)d_out;

    char* w = (char*)d_ws;
    const size_t M1 = (size_t)1 << 20;
    ushort_t* XH  = (ushort_t*)(w);              // [0,8M)   x hi
    ushort_t* XL  = (ushort_t*)(w + 8  * M1);    // [8,16M)  x lo
    ushort_t* WqH = (ushort_t*)(w + 16 * M1);    // [16,18M)
    ushort_t* WqL = (ushort_t*)(w + 18 * M1);
    ushort_t* WkH = (ushort_t*)(w + 20 * M1);
    ushort_t* WkL = (ushort_t*)(w + 22 * M1);
    ushort_t* WvH = (ushort_t*)(w + 24 * M1);
    ushort_t* WuH = (ushort_t*)(w + 26 * M1);
    ushort_t* QHb = (ushort_t*)(w + 28 * M1);    // [28,36M)
    ushort_t* QLb = (ushort_t*)(w + 36 * M1);
    ushort_t* KHb = (ushort_t*)(w + 44 * M1);
    ushort_t* KLb = (ushort_t*)(w + 52 * M1);    // ..60M
    ushort_t* VTb = (ushort_t*)(w + 16 * M1);    // over Wq/Wk (dead after QK gemm)
    ushort_t* YHb = (ushort_t*)(w);              // over XH (dead after V gemm)

    dim3 blk(256);
    conv_all<<<dim3(4096, 5), blk, 0, stream>>>(x, Wq, Wk, Wv, Wu,
                                                XH, XL, WqH, WqL, WkH, WkL, WvH, WuH);
    gemm_bf16<<<dim3(8, 32, 2), blk, 0, stream>>>(XH, XL, WqH, WqL, WkH, WkL, WvH, WuH,
                                                  QHb, QLb, KHb, KLb, nullptr, nullptr,
                                                  nullptr, 0);
    gemm_bf16<<<dim3(8, 32, 1), blk, 0, stream>>>(XH, XL, WqH, WqL, WkH, WkL, WvH, WuH,
                                                  nullptr, nullptr, nullptr, nullptr, VTb,
                                                  nullptr, nullptr, 2);
    attn_mfma<<<dim3(32, NH, 2), blk, 0, stream>>>(QHb, QLb, KHb, KLb, VTb, mask, YHb);
    gemm_bf16<<<dim3(8, 32, 1), blk, 0, stream>>>(YHb, nullptr, WqH, WqL, WkH, WkL, WvH, WuH,
                                                  nullptr, nullptr, nullptr, nullptr, nullptr,
                                                  out, bu, 3);
}

// Round 6
// 303.595 us; speedup vs baseline: 3.3518x; 1.0477x over previous
//
#include <hip/hip_runtime.h>
#include <hip/hip_bf16.h>
#include <math.h>

#define TS 2048   // sequence length T
#define KD 1024   // model dim K
#define NH 16     // heads
#define SD 64     // head dim
#define MB 4096   // B*T rows
#define LOG2E 1.4426950408889634f

typedef __attribute__((ext_vector_type(8))) short bf16x8;   // 8 bf16 (4 VGPRs)
typedef __attribute__((ext_vector_type(4))) short bf16x4;   // 4 bf16 (2 VGPRs)
typedef __attribute__((ext_vector_type(4))) float f32x4;    // MFMA accumulator
typedef unsigned short ushort_t;

#define MFMA32(a, b, c) __builtin_amdgcn_mfma_f32_16x16x32_bf16(a, b, c, 0, 0, 0)

union frag8 { bf16x8 v8; bf16x4 h[2]; };

__device__ __forceinline__ ushort_t f2bf_rn(float f) {
    union { __hip_bfloat16 h; ushort_t u; } c;
    c.h = __float2bfloat16(f);
    return c.u;
}
__device__ __forceinline__ float bf2f(ushort_t u) {
    union { unsigned u; float f; } v; v.u = ((unsigned)u) << 16;
    return v.f;
}
__device__ __forceinline__ ushort4 pk4_bf(float a, float b, float c, float d) {
    union { __hip_bfloat162 h; ushort2 u; } x, y;
    x.h = __float22bfloat162_rn(make_float2(a, b));
    y.h = __float22bfloat162_rn(make_float2(c, d));
    return make_ushort4(x.u.x, x.u.y, y.u.x, y.u.y);
}
// async global -> LDS, 16 B per lane; lds ptr must be wave-uniform
__device__ __forceinline__ void gload_lds16(const void* g, void* l) {
    __builtin_amdgcn_global_load_lds(
        (const __attribute__((address_space(1))) unsigned int*)g,
        (__attribute__((address_space(3))) unsigned int*)l, 16, 0, 0);
}

// ---------------------------------------------------------------------------
// conv_all: z=0: x -> XH,XL (hi/lo); z=1: Wq*log2e -> hi/lo (folds exp->exp2);
// z=2: Wk -> hi/lo; z=3: Wv -> hi; z=4: Wu -> hi.
// ---------------------------------------------------------------------------
__global__ __launch_bounds__(256)
void conv_all(const float* __restrict__ x, const float* __restrict__ wq,
              const float* __restrict__ wk, const float* __restrict__ wv,
              const float* __restrict__ wu,
              ushort_t* XH, ushort_t* XL, ushort_t* WqH, ushort_t* WqL,
              ushort_t* WkH, ushort_t* WkL, ushort_t* WvH, ushort_t* WuH)
{
    int z = blockIdx.y;
    const float* src; ushort_t* H; ushort_t* L = nullptr; int nblk;
    switch (z) {
        case 0:  src = x;  H = XH;  L = XL;  nblk = 4096; break;
        case 1:  src = wq; H = WqH; L = WqL; nblk = 1024; break;
        case 2:  src = wk; H = WkH; L = WkL; nblk = 1024; break;
        case 3:  src = wv; H = WvH;          nblk = 1024; break;
        default: src = wu; H = WuH;          nblk = 1024; break;
    }
    if ((int)blockIdx.x >= nblk) return;
    int idx = blockIdx.x * 256 + threadIdx.x;      // float4 index
    float4 v = ((const float4*)src)[idx];
    if (z == 1) { v.x *= LOG2E; v.y *= LOG2E; v.z *= LOG2E; v.w *= LOG2E; }
    ushort_t h0 = f2bf_rn(v.x), h1 = f2bf_rn(v.y);
    ushort_t h2 = f2bf_rn(v.z), h3 = f2bf_rn(v.w);
    ((ushort4*)H)[idx] = make_ushort4(h0, h1, h2, h3);
    if (L) {
        ushort_t l0 = f2bf_rn(v.x - bf2f(h0)), l1 = f2bf_rn(v.y - bf2f(h1));
        ushort_t l2 = f2bf_rn(v.z - bf2f(h2)), l3 = f2bf_rn(v.w - bf2f(h3));
        ((ushort4*)L)[idx] = make_ushort4(l0, l1, l2, l3);
    }
}

// ---------------------------------------------------------------------------
// MFMA GEMM: C = A @ W^T. 64x128 tile, BK=32, 4 waves (2x2), 32x64/wave.
// Grid: x=8 (N/128), y=64 (M/64), z = epi selector. 24 KB LDS -> 6 blocks/CU.
// epi 0/1: hi/lo bf16 out (Q/K); epi 2: transposed Vt; epi 3: fp32+bias out.
// ---------------------------------------------------------------------------
__global__ __launch_bounds__(256)
void gemm_bf16(const ushort_t* __restrict__ Ah, const ushort_t* __restrict__ Al,
               const ushort_t* __restrict__ Bqh, const ushort_t* __restrict__ Bql,
               const ushort_t* __restrict__ Bkh, const ushort_t* __restrict__ Bkl,
               const ushort_t* __restrict__ Bvh, const ushort_t* __restrict__ Buh,
               ushort_t* __restrict__ OQh, ushort_t* __restrict__ OQl,
               ushort_t* __restrict__ OKh, ushort_t* __restrict__ OKl,
               ushort_t* __restrict__ OVt, float* __restrict__ OF,
               const float* __restrict__ bias, int epi_base)
{
    const int epi = epi_base + blockIdx.z;
    const ushort_t* Bh; const ushort_t* Bl = nullptr;
    if      (epi == 0) { Bh = Bqh; Bl = Bql; }
    else if (epi == 1) { Bh = Bkh; Bl = Bkl; }
    else if (epi == 2) { Bh = Bvh; }
    else               { Bh = Buh; }
    const bool terms3 = (epi < 2);

    __shared__ ushort_t sAh[64 * 32];    // 4 KB
    __shared__ ushort_t sAl[64 * 32];
    __shared__ ushort_t sBh[128 * 32];   // 8 KB
    __shared__ ushort_t sBl[128 * 32];

    const int tid = threadIdx.x;
    const int wave = tid >> 6, lane = tid & 63;
    const int col = lane & 15, quad = lane >> 4;
    const int wm = wave >> 1, wn = wave & 1;
    const int m0 = blockIdx.y * 64, n0 = blockIdx.x * 128;

    f32x4 acc[2][4];
#pragma unroll
    for (int i = 0; i < 2; ++i)
#pragma unroll
        for (int j = 0; j < 4; ++j) acc[i][j] = (f32x4){0.f, 0.f, 0.f, 0.f};

    for (int k0 = 0; k0 < KD; k0 += 32) {
        {   // A tile: 256 16B-slots, one per thread
            int row = tid >> 2, k8 = tid & 3;
            int lo  = wave * 64 * 8;                  // wave-uniform ushort offset
            gload_lds16(Ah + (size_t)(m0 + row) * KD + k0 + k8 * 8, sAh + lo);
            if (terms3)
                gload_lds16(Al + (size_t)(m0 + row) * KD + k0 + k8 * 8, sAl + lo);
        }
#pragma unroll
        for (int j = 0; j < 2; ++j) {   // B tile: 512 slots
            int s   = wave * 128 + j * 64 + lane;
            int row = s >> 2, k8 = s & 3;
            int lo  = (wave * 128 + j * 64) * 8;
            gload_lds16(Bh + (size_t)(n0 + row) * KD + k0 + k8 * 8, sBh + lo);
            if (terms3)
                gload_lds16(Bl + (size_t)(n0 + row) * KD + k0 + k8 * 8, sBl + lo);
        }
        __syncthreads();

        bf16x8 fbh[4], fbl[4];
#pragma unroll
        for (int j = 0; j < 4; ++j) {
            int r = (wn * 64 + j * 16 + col) * 32 + quad * 8;
            fbh[j] = *(const bf16x8*)&sBh[r];
            if (terms3) fbl[j] = *(const bf16x8*)&sBl[r];
        }
#pragma unroll
        for (int i = 0; i < 2; ++i) {
            int r = (wm * 32 + i * 16 + col) * 32 + quad * 8;
            bf16x8 fah = *(const bf16x8*)&sAh[r];
            if (terms3) {
                bf16x8 fal = *(const bf16x8*)&sAl[r];
#pragma unroll
                for (int j = 0; j < 4; ++j) {
                    acc[i][j] = MFMA32(fah, fbh[j], acc[i][j]);
                    acc[i][j] = MFMA32(fah, fbl[j], acc[i][j]);
                    acc[i][j] = MFMA32(fal, fbh[j], acc[i][j]);
                }
            } else {
#pragma unroll
                for (int j = 0; j < 4; ++j)
                    acc[i][j] = MFMA32(fah, fbh[j], acc[i][j]);
            }
        }
        __syncthreads();
    }

    // ---- epilogues (C/D: row m = quad*4+reg, col n = lane&15) ----
    if (epi <= 1) {
        ushort_t* OH = (epi == 0) ? OQh : OKh;
        ushort_t* OL = (epi == 0) ? OQl : OKl;
#pragma unroll
        for (int i = 0; i < 2; ++i) {
            int m = m0 + wm * 32 + i * 16 + quad * 4;
#pragma unroll
            for (int j = 0; j < 4; ++j) {
                int n = n0 + wn * 64 + j * 16 + col;
#pragma unroll
                for (int r = 0; r < 4; ++r) {
                    float v = acc[i][j][r];
                    ushort_t hv = f2bf_rn(v);
                    size_t off = (size_t)(m + r) * KD + n;
                    OH[off] = hv;
                    OL[off] = f2bf_rn(v - bf2f(hv));
                }
            }
        }
    } else if (epi == 2) {
#pragma unroll
        for (int i = 0; i < 2; ++i) {
            int m = m0 + wm * 32 + i * 16 + quad * 4;
            int bb = m >> 11, t = m & (TS - 1);
#pragma unroll
            for (int j = 0; j < 4; ++j) {
                int n = n0 + wn * 64 + j * 16 + col;
                int hh = n >> 6, d = n & 63;
                ushort4 pk = pk4_bf(acc[i][j][0], acc[i][j][1], acc[i][j][2], acc[i][j][3]);
                *(ushort4*)(OVt + ((size_t)(bb * NH + hh) * SD + d) * TS + t) = pk;
            }
        }
    } else {
#pragma unroll
        for (int i = 0; i < 2; ++i) {
            int m = m0 + wm * 32 + i * 16 + quad * 4;
#pragma unroll
            for (int j = 0; j < 4; ++j) {
                int n = n0 + wn * 64 + j * 16 + col;
                float bj = bias[n];
#pragma unroll
                for (int r = 0; r < 4; ++r)
                    OF[(size_t)(m + r) * KD + n] = acc[i][j][r] + bj;
            }
        }
    }
}

// ---------------------------------------------------------------------------
// MFMA flash attention (keys distributed across waves), round-6 tuning:
// mask folded into S accumulator init (-inf -> exp2=0, no cndmask per elem);
// persistent zero upper halves for zero-padded PV fragments; staging pointers
// hoisted (6 ptr bumps/kt); O-reduce staged through 16 KB -> LDS 25 KB.
// ---------------------------------------------------------------------------
__global__ __launch_bounds__(256, 2)
void attn_mfma(const ushort_t* __restrict__ QH, const ushort_t* __restrict__ QL,
               const ushort_t* __restrict__ KH, const ushort_t* __restrict__ KL,
               const ushort_t* __restrict__ VT, const int* __restrict__ mask,
               ushort_t* __restrict__ YH)
{
    const int qt = blockIdx.x;       // 0..31
    const int h  = blockIdx.y;
    const int b  = blockIdx.z;
    const int bh = b * NH + h;

    const int tid  = threadIdx.x;
    const int wave = tid >> 6;
    const int lane = tid & 63;
    const int col  = lane & 15;
    const int quad = lane >> 4;

    __shared__ ushort_t smem[12288];     // 24 KB: staging; reused for O-reduce
    ushort_t* sKH = smem;                // [key][d] swizzled, 8 KB
    ushort_t* sKL = smem + 4096;
    ushort_t* sVT = smem + 8192;         // [d][key] swizzled, 8 KB
    __shared__ float lred[4][64];

    // ---- Q fragments, held in registers for the whole kernel ----
    bf16x8 bqh[4][2], bql[4][2];
#pragma unroll
    for (int qf = 0; qf < 4; ++qf) {
        size_t qrow = (size_t)(b * TS + qt * 64 + qf * 16 + col) * KD + h * SD;
#pragma unroll
        for (int c = 0; c < 2; ++c) {
            bqh[qf][c] = *(const bf16x8*)(QH + qrow + c * 32 + quad * 8);
            bql[qf][c] = *(const bf16x8*)(QL + qrow + c * 32 + quad * 8);
        }
    }

    // ---- hoisted staging pointers: chunk r -> {r<2: KH, r<4: KL, else VT} ----
    const int l8 = lane >> 3, l7 = lane & 7;
    const ushort_t* gp[6];
    ushort_t* ld[6];
#pragma unroll
    for (int r = 0; r < 6; ++r) {
        int cc  = (r & 1) * 4 + wave;          // chunk within its matrix (0..7)
        int row = cc * 8 + l8;                 // 0..63
        int gs  = l7 ^ (row & 7);              // XOR swizzle
        if (r < 2)      gp[r] = KH + (size_t)(b * TS + row) * KD + h * SD + gs * 8;
        else if (r < 4) gp[r] = KL + (size_t)(b * TS + row) * KD + h * SD + gs * 8;
        else            gp[r] = VT + ((size_t)bh * SD + row) * TS + gs * 8;
        ld[r] = ((r < 2) ? sKH : (r < 4) ? sKL : sVT) + cc * 512;
    }
    const int* mp = mask + b * TS + wave * 16 + quad * 4;

    float lp[4] = {0.f, 0.f, 0.f, 0.f};
    f32x4 O[4][4];                        // [dt][qf], O^T: row=d, col=q
#pragma unroll
    for (int dt = 0; dt < 4; ++dt)
#pragma unroll
        for (int qf = 0; qf < 4; ++qf) O[dt][qf] = (f32x4){0.f, 0.f, 0.f, 0.f};

    frag8 av[4], bp4[4];
#pragma unroll
    for (int i = 0; i < 4; ++i) {
        av[i].v8  = (bf16x8){0, 0, 0, 0, 0, 0, 0, 0};
        bp4[i].v8 = (bf16x8){0, 0, 0, 0, 0, 0, 0, 0};
    }

    for (int kt = 0; kt < TS / 64; ++kt) {
#pragma unroll
        for (int r = 0; r < 6; ++r) gload_lds16(gp[r], ld[r]);
        int4 mv = *(const int4*)mp;
        mp += 64;
#pragma unroll
        for (int r = 0; r < 6; ++r) gp[r] += (r < 4) ? 64 * KD : 64;
        __syncthreads();

        // masked keys: S starts at -inf -> exp2 gives exactly 0
        f32x4 sinit;
        sinit[0] = mv.x ? 0.f : -INFINITY;
        sinit[1] = mv.y ? 0.f : -INFINITY;
        sinit[2] = mv.z ? 0.f : -INFINITY;
        sinit[3] = mv.w ? 0.f : -INFINITY;

        // ---- K / V fragments for this wave's 16-key strip ----
        bf16x8 akh[2], akl[2];
#pragma unroll
        for (int c = 0; c < 2; ++c) {
            int sl = (c * 4 + quad) ^ (col & 7);
            akh[c] = *(const bf16x8*)&sKH[((wave * 16 + col) * 8 + sl) * 8];
            akl[c] = *(const bf16x8*)&sKL[((wave * 16 + col) * 8 + sl) * 8];
        }
#pragma unroll
        for (int dt = 0; dt < 4; ++dt) {
            int sl = (wave * 2 + (quad >> 1)) ^ (col & 7);
            av[dt].h[0] = *(const bf16x4*)&sVT[((dt * 16 + col) * 8 + sl) * 8 + (quad & 1) * 4];
        }

        // ---- S^T strips (hi/lo 3-term, 2 indep chains) + exp2 + pack P ----
#pragma unroll
        for (int qf = 0; qf < 4; ++qf) {
            f32x4 s1 = sinit;
            f32x4 s2 = (f32x4){0.f, 0.f, 0.f, 0.f};
            s1 = MFMA32(akh[0], bqh[qf][0], s1);
            s2 = MFMA32(akl[0], bqh[qf][0], s2);
            s2 = MFMA32(akh[0], bql[qf][0], s2);
            s1 = MFMA32(akh[1], bqh[qf][1], s1);
            s2 = MFMA32(akl[1], bqh[qf][1], s2);
            s2 = MFMA32(akh[1], bql[qf][1], s2);
            float p0 = exp2f(s1[0] + s2[0]);
            float p1 = exp2f(s1[1] + s2[1]);
            float p2 = exp2f(s1[2] + s2[2]);
            float p3 = exp2f(s1[3] + s2[3]);
            lp[qf] += (p0 + p1) + (p2 + p3);
            union { ushort4 u4; bf16x4 v4; } pk;
            pk.u4 = pk4_bf(p0, p1, p2, p3);
            bp4[qf].h[0] = pk.v4;
        }

        // ---- O^T += V^T x P^T (zero-padded K=32 MFMA, P direct from regs) ----
#pragma unroll
        for (int dt = 0; dt < 4; ++dt)
#pragma unroll
            for (int qf = 0; qf < 4; ++qf)
                O[dt][qf] = MFMA32(av[dt].v8, bp4[qf].v8, O[dt][qf]);

        __syncthreads();
    }

    // ---- l: reduce over quads, publish per wave ----
#pragma unroll
    for (int qf = 0; qf < 4; ++qf) {
        float v = lp[qf];
        v += __shfl_xor(v, 16);
        v += __shfl_xor(v, 32);
        if (lane < 16) lred[wave][qf * 16 + lane] = v;
    }

    // ---- staged O-reduce through 16 KB of smem (3 rounds) ----
    float* Of = (float*)smem;
#pragma unroll
    for (int w = 1; w < 4; ++w) {
        __syncthreads();
        if (wave == w) {
#pragma unroll
            for (int dt = 0; dt < 4; ++dt)
#pragma unroll
                for (int qf = 0; qf < 4; ++qf)
                    *(f32x4*)&Of[((dt * 4 + qf) * 64 + lane) * 4] = O[dt][qf];
        }
        __syncthreads();
        if (wave == 0) {
#pragma unroll
            for (int dt = 0; dt < 4; ++dt)
#pragma unroll
                for (int qf = 0; qf < 4; ++qf)
                    O[dt][qf] += *(const f32x4*)&Of[((dt * 4 + qf) * 64 + lane) * 4];
        }
    }
    if (wave == 0) {
        float linv[4];
#pragma unroll
        for (int qf = 0; qf < 4; ++qf) {
            int q = qf * 16 + col;
            linv[qf] = 1.f / (lred[0][q] + lred[1][q] + lred[2][q] + lred[3][q]);
        }
#pragma unroll
        for (int dt = 0; dt < 4; ++dt)
#pragma unroll
            for (int qf = 0; qf < 4; ++qf) {
                ushort4 pk = pk4_bf(O[dt][qf][0] * linv[qf], O[dt][qf][1] * linv[qf],
                                    O[dt][qf][2] * linv[qf], O[dt][qf][3] * linv[qf]);
                *(ushort4*)(YH + (size_t)(b * TS + qt * 64 + qf * 16 + col) * KD +
                            h * SD + dt * 16 + quad * 4) = pk;
            }
    }
}

// ---------------------------------------------------------------------------
extern "C" void kernel_launch(void* const* d_in, const int* in_sizes, int n_in,
                              void* d_out, int out_size, void* d_ws, size_t ws_size,
                              hipStream_t stream) {
    const float* x    = (const float*)d_in[0];
    const int*   mask = (const int*)d_in[1];
    const float* Wk   = (const float*)d_in[2];
    const float* Wq   = (const float*)d_in[3];
    const float* Wv   = (const float*)d_in[4];
    const float* Wu   = (const float*)d_in[5];
    const float* bu   = (const float*)d_in[6];
    float* out = (float*)d_out;

    char* w = (char*)d_ws;
    const size_t M1 = (size_t)1 << 20;
    // workspace plan (60 MB peak; VT lives in d_out until the U gemm):
    ushort_t* XH  = (ushort_t*)(w);              // [0,8M)
    ushort_t* XL  = (ushort_t*)(w + 8  * M1);    // [8,16M)
    ushort_t* WqH = (ushort_t*)(w + 16 * M1);
    ushort_t* WqL = (ushort_t*)(w + 18 * M1);
    ushort_t* WkH = (ushort_t*)(w + 20 * M1);
    ushort_t* WkL = (ushort_t*)(w + 22 * M1);
    ushort_t* WvH = (ushort_t*)(w + 24 * M1);    // [24,26M)
    ushort_t* QHb = (ushort_t*)(w + 26 * M1);    // [26,34M)
    ushort_t* QLb = (ushort_t*)(w + 34 * M1);
    ushort_t* KHb = (ushort_t*)(w + 42 * M1);
    ushort_t* KLb = (ushort_t*)(w + 50 * M1);    // ..58M
    ushort_t* WuH = (ushort_t*)(w + 58 * M1);    // [58,60M)
    ushort_t* VTb = (ushort_t*)d_out;            // 8 MB scratch in d_out
    ushort_t* YHb = (ushort_t*)(w);              // over XH (dead after QKV)

    dim3 blk(256);
    conv_all<<<dim3(4096, 5), blk, 0, stream>>>(x, Wq, Wk, Wv, Wu,
                                                XH, XL, WqH, WqL, WkH, WkL, WvH, WuH);
    // fused Q,K,V projections: 1536 blocks = 6/CU
    gemm_bf16<<<dim3(8, 64, 3), blk, 0, stream>>>(XH, XL, WqH, WqL, WkH, WkL, WvH, WuH,
                                                  QHb, QLb, KHb, KLb, VTb, nullptr,
                                                  nullptr, 0);
    attn_mfma<<<dim3(32, NH, 2), blk, 0, stream>>>(QHb, QLb, KHb, KLb, VTb, mask, YHb);
    // output projection + bias: 512 blocks = 2/CU
    gemm_bf16<<<dim3(8, 64, 1), blk, 0, stream>>>(YHb, nullptr, WqH, WqL, WkH, WkL, WvH, WuH,
                                                  nullptr, nullptr, nullptr, nullptr, nullptr,
                                                  out, bu, 3);
}